// Round 11
// baseline (249.970 us; speedup 1.0000x reference)
//
#include <hip/hip_runtime.h>

typedef __attribute__((ext_vector_type(8))) short short8;
typedef __attribute__((ext_vector_type(4))) float f32x4;
typedef __attribute__((ext_vector_type(16))) float f32x16;

#define T_TOK 16384
#define DM 512
#define NE 8
#define BM 64
#define ROWB 1040  // padded LDS row stride: 65*16B

__device__ __forceinline__ ushort f2bf(float v) {
  unsigned u = __float_as_uint(v);
  return (ushort)((u + 0x7FFFu + ((u >> 16) & 1u)) >> 16);
}

__device__ __forceinline__ unsigned pk2bf(float a, float b) {
  unsigned r;
  asm("v_cvt_pk_bf16_f32 %0, %1, %2" : "=v"(r) : "v"(a), "v"(b));
  return r;
}

#define MF(d, a, b) d = __builtin_amdgcn_mfma_f32_32x32x16_bf16(a, b, d, 0, 0, 0)

// ---------------- gating: logits + softmax, one wave per token ----------------
__global__ void gates_kernel(const float* __restrict__ x, const float* __restrict__ Wg,
                             const float* __restrict__ bg, float* __restrict__ gates) {
  int wid = (int)((blockIdx.x * blockDim.x + threadIdx.x) >> 6);
  int lane = threadIdx.x & 63;
  if (wid >= T_TOK) return;
  const float* xt = x + (size_t)wid * DM;
  float a[NE];
#pragma unroll
  for (int e = 0; e < NE; ++e) a[e] = 0.f;
  for (int d = lane; d < DM; d += 64) {
    float xv = xt[d];
    const float* wr = Wg + d * NE;
#pragma unroll
    for (int e = 0; e < NE; ++e) a[e] += xv * wr[e];
  }
#pragma unroll
  for (int e = 0; e < NE; ++e) {
#pragma unroll
    for (int off = 32; off > 0; off >>= 1) a[e] += __shfl_xor(a[e], off, 64);
  }
  float m = -1e30f;
#pragma unroll
  for (int e = 0; e < NE; ++e) { a[e] += bg[e]; m = fmaxf(m, a[e]); }
  float s = 0.f;
#pragma unroll
  for (int e = 0; e < NE; ++e) { a[e] = __expf(a[e] - m); s += a[e]; }
  float inv = 1.f / s;
  if (lane < NE) gates[(size_t)wid * NE + lane] = a[lane] * inv;
}

// -------- weight reorder: W[e][k][n] fp32 -> 32x32x16 A-fragment-major bf16 ----
__global__ void reorder_w_kernel(const float* __restrict__ W, ushort* __restrict__ WF) {
  int c = blockIdx.x * blockDim.x + threadIdx.x;  // 262144 threads
  int l = c & 63;
  int chunk = c >> 6;
  int ft = chunk & 15;
  int kh = (chunk >> 4) & 31;
  int e = chunk >> 9;
  int n = ft * 32 + (l & 31);
  int k0 = kh * 16 + (l >> 5) * 8;
  const float* src = W + ((size_t)e * DM + k0) * DM + n;
  short8 v;
#pragma unroll
  for (int j = 0; j < 8; ++j) v[j] = (short)f2bf(src[(size_t)j * DM]);
  *reinterpret_cast<short8*>(WF + (size_t)c * 8) = v;
}

// -------- x reorder: x fp32 -> 32x32x16 B-fragment-major bf16 --------
// EXACTLY 1,048,576 threads. Grid must be 4096 x 256.
__global__ void reorder_x_kernel(const float* __restrict__ x, ushort* __restrict__ XF) {
  int c = blockIdx.x * blockDim.x + threadIdx.x;
  int l = c & 63;
  int ni = (c >> 6) & 1;
  int ks = (c >> 7) & 1;
  int kt = (c >> 8) & 15;
  int m = c >> 12;  // < 256
  int t = m * 64 + ni * 32 + (l & 31);
  int k0 = kt * 32 + ks * 16 + (l >> 5) * 8;
  const float* src = x + (size_t)t * DM + k0;
  short8 v;
#pragma unroll
  for (int j = 0; j < 8; ++j) v[j] = (short)f2bf(src[j]);
  *reinterpret_cast<short8*>(XF + (size_t)c * 8) = v;
}

// GEMM1 16-kt loop: weights from wp (W1F, global), acts from xfp (XF, global)
__device__ __forceinline__ void g1_gemm(const short8* __restrict__ wp,
                                        const short8* __restrict__ xfp,
                                        short8 (&wb)[3][4], short8 (&ab)[2][4],
                                        f32x16 (&hacc)[2][2]) {
#pragma unroll
  for (int ks = 0; ks < 2; ++ks)
#pragma unroll
    for (int mi = 0; mi < 2; ++mi) {
      wb[2][ks * 2 + mi] = wp[ks * 1024 + mi * 64];
      wb[0][ks * 2 + mi] = wp[2048 + ks * 1024 + mi * 64];
    }
#pragma unroll
  for (int ks = 0; ks < 2; ++ks)
#pragma unroll
    for (int ni = 0; ni < 2; ++ni) ab[0][ks * 2 + ni] = xfp[(ks * 2 + ni) * 64];
#pragma unroll
  for (int kt = 0; kt < 16; ++kt) {
    if (kt < 14) {
#pragma unroll
      for (int ks = 0; ks < 2; ++ks)
#pragma unroll
        for (int mi = 0; mi < 2; ++mi)
          wb[(kt + 1) % 3][ks * 2 + mi] = wp[(kt + 2) * 2048 + ks * 1024 + mi * 64];
    }
    if (kt < 15) {
#pragma unroll
      for (int ks = 0; ks < 2; ++ks)
#pragma unroll
        for (int ni = 0; ni < 2; ++ni)
          ab[(kt + 1) & 1][ks * 2 + ni] = xfp[((kt + 1) * 4 + ks * 2 + ni) * 64];
    }
    __builtin_amdgcn_s_setprio(1);
#pragma unroll
    for (int ks = 0; ks < 2; ++ks)
#pragma unroll
      for (int mi = 0; mi < 2; ++mi)
#pragma unroll
        for (int ni = 0; ni < 2; ++ni)
          MF(hacc[mi][ni], wb[(kt + 2) % 3][ks * 2 + mi], ab[kt % 2][ks * 2 + ni]);
    __builtin_amdgcn_s_setprio(0);
  }
}

// GEMM2 16-kt loop: weights from we2 (global, wb[1]/wb[2] pre-primed with kt0/kt1),
// acts from h LDS buffer.
__device__ __forceinline__ void g2_gemm(const short8* __restrict__ we2,
                                        const char* __restrict__ hsrc, unsigned abase,
                                        short8 (&wb)[3][4], short8 (&ab)[2][4],
                                        f32x16 (&acc)[2][2]) {
#pragma unroll
  for (int ks = 0; ks < 2; ++ks)
#pragma unroll
    for (int ni = 0; ni < 2; ++ni)
      ab[0][ks * 2 + ni] = *reinterpret_cast<const short8*>(
          hsrc + abase + ni * (32 * ROWB) + ks * 32);
#pragma unroll
  for (int kt = 0; kt < 16; ++kt) {
    if (kt < 14) {
#pragma unroll
      for (int ks = 0; ks < 2; ++ks)
#pragma unroll
        for (int mi = 0; mi < 2; ++mi)
          wb[kt % 3][ks * 2 + mi] = we2[(kt + 2) * 2048 + ks * 1024 + mi * 64];
    }
    if (kt < 15) {
#pragma unroll
      for (int ks = 0; ks < 2; ++ks)
#pragma unroll
        for (int ni = 0; ni < 2; ++ni)
          ab[(kt + 1) & 1][ks * 2 + ni] = *reinterpret_cast<const short8*>(
              hsrc + abase + ni * (32 * ROWB) + (kt + 1) * 64 + ks * 32);
    }
    __builtin_amdgcn_s_setprio(1);
#pragma unroll
    for (int ks = 0; ks < 2; ++ks)
#pragma unroll
      for (int mi = 0; mi < 2; ++mi)
#pragma unroll
        for (int ni = 0; ni < 2; ++ni)
          MF(acc[mi][ni], wb[(kt + 1) % 3][ks * 2 + mi], ab[kt % 2][ks * 2 + ni]);
    __builtin_amdgcn_s_setprio(0);
  }
}

// ---------------- fused MoE main kernel ----------------
// 256 blocks x 512 threads (8 waves). Wave w owns cols [w*64, w*64+64).
// h double-buffered in LDS; x-frags from XF (global/L2); ONE barrier per expert:
// segment e = [G2(e) | G1(e+1) | epi(e+1) -> hb[(e+1)&1]] ; BAR.
__global__ __launch_bounds__(512, 2) void moe_main_kernel(
    const ushort* __restrict__ XF, const ushort* __restrict__ W1F,
    const float* __restrict__ b1, const ushort* __restrict__ W2F,
    const float* __restrict__ b2, const float* __restrict__ gates,
    float* __restrict__ out) {
  extern __shared__ char smem[];
  char* hb0 = smem;                           // 66560
  char* hb1 = smem + 66560;                   // 66560
  float* g_lds = (float*)(smem + 133120);     // [64][9] f32 = 2304
  float* b1_lds = (float*)(smem + 135424);    // [8][512] f32 = 16384

  const int tid = threadIdx.x;
  const int lane = tid & 63;
  const int w = tid >> 6;
  const int hi = lane >> 5;
  const int l31 = lane & 31;
  const int m0 = blockIdx.x * BM;

  const unsigned abase = (unsigned)l31 * ROWB + (unsigned)hi * 16;
  const unsigned wbase = (unsigned)l31 * ROWB + (unsigned)(w * 128 + hi * 8);

#define BARRIER()                                        \
  do {                                                   \
    asm volatile("s_waitcnt lgkmcnt(0)" ::: "memory");   \
    __builtin_amdgcn_s_barrier();                        \
  } while (0)

  {  // gates -> LDS (padded stride 9)
    int t = tid >> 3, e = tid & 7;
    g_lds[t * 9 + e] = gates[(size_t)(m0 + t) * NE + e];
  }
  {  // b1 -> LDS (4096 floats, broadcast-read later)
    float4* dst = (float4*)b1_lds;
    const float4* src = (const float4*)b1;
    dst[tid] = src[tid];
    dst[tid + 512] = src[tid + 512];
  }

  const short8* wp1 = reinterpret_cast<const short8*>(W1F) + w * 128 + lane;
  const short8* wp2 = reinterpret_cast<const short8*>(W2F) + w * 128 + lane;
  const short8* xfp = reinterpret_cast<const short8*>(XF) + (size_t)blockIdx.x * 4096 + lane;

  f32x16 acc[2][2], hacc[2][2];
#pragma unroll
  for (int mi = 0; mi < 2; ++mi)
#pragma unroll
    for (int ni = 0; ni < 2; ++ni)
#pragma unroll
      for (int i = 0; i < 16; ++i) { acc[mi][ni][i] = 0.f; hacc[mi][ni][i] = 0.f; }

  short8 wb[3][4], ab[2][4];

  BARRIER();  // g_lds / b1_lds staged

  // ---------- G1(0) ----------
  g1_gemm(wp1, xfp, wb, ab, hacc);

  // W2(0) kt0/kt1 prologue (stays in flight across epi + barrier)
#pragma unroll
  for (int ks = 0; ks < 2; ++ks)
#pragma unroll
    for (int mi = 0; mi < 2; ++mi) {
      wb[1][ks * 2 + mi] = wp2[ks * 1024 + mi * 64];
      wb[2][ks * 2 + mi] = wp2[2048 + ks * 1024 + mi * 64];
    }

  // epi(0): h0 = relu(hacc + b1[0]) * g -> hb0
#pragma unroll
  for (int ni = 0; ni < 2; ++ni) {
    int t = ni * 32 + l31;
    float g = g_lds[t * 9 + 0];
#pragma unroll
    for (int mi = 0; mi < 2; ++mi) {
#pragma unroll
      for (int j = 0; j < 4; ++j) {
        float4 b1q = *reinterpret_cast<const float4*>(
            b1_lds + 0 * DM + w * 64 + mi * 32 + j * 8 + hi * 4);
        float v0 = fmaxf(hacc[mi][ni][j * 4 + 0] + b1q.x, 0.f) * g;
        float v1 = fmaxf(hacc[mi][ni][j * 4 + 1] + b1q.y, 0.f) * g;
        float v2 = fmaxf(hacc[mi][ni][j * 4 + 2] + b1q.z, 0.f) * g;
        float v3 = fmaxf(hacc[mi][ni][j * 4 + 3] + b1q.w, 0.f) * g;
        *reinterpret_cast<uint2*>(hb0 + wbase + ni * (32 * ROWB) + mi * 64 + j * 16) =
            make_uint2(pk2bf(v0, v1), pk2bf(v2, v3));
      }
    }
  }
  BARRIER();  // hb0 ready

  for (int e = 0; e < NE; ++e) {
    const short8* we2 = wp2 + (size_t)e * 32768;
    char* hsrc = (e & 1) ? hb1 : hb0;

    // ---------- G2(e) ----------
    g2_gemm(we2, hsrc, abase, wb, ab, acc);

    if (e < NE - 1) {
      // ---------- G1(e+1) (global reads only; no barrier needed) ----------
#pragma unroll
      for (int mi = 0; mi < 2; ++mi)
#pragma unroll
        for (int ni = 0; ni < 2; ++ni)
#pragma unroll
          for (int i = 0; i < 16; ++i) hacc[mi][ni][i] = 0.f;
      g1_gemm(wp1 + (size_t)(e + 1) * 32768, xfp, wb, ab, hacc);

      // W2(e+1) kt0/kt1 prologue (in flight across epi + barrier)
      const short8* wn2 = we2 + 32768;
#pragma unroll
      for (int ks = 0; ks < 2; ++ks)
#pragma unroll
        for (int mi = 0; mi < 2; ++mi) {
          wb[1][ks * 2 + mi] = wn2[ks * 1024 + mi * 64];
          wb[2][ks * 2 + mi] = wn2[2048 + ks * 1024 + mi * 64];
        }

      // epi(e+1) -> hb[(e+1)&1]  (WAR safe: last readers G2(e-1) fenced by prev BAR)
      char* hdst = ((e + 1) & 1) ? hb1 : hb0;
#pragma unroll
      for (int ni = 0; ni < 2; ++ni) {
        int t = ni * 32 + l31;
        float g = g_lds[t * 9 + (e + 1)];
#pragma unroll
        for (int mi = 0; mi < 2; ++mi) {
#pragma unroll
          for (int j = 0; j < 4; ++j) {
            float4 b1q = *reinterpret_cast<const float4*>(
                b1_lds + (e + 1) * DM + w * 64 + mi * 32 + j * 8 + hi * 4);
            float v0 = fmaxf(hacc[mi][ni][j * 4 + 0] + b1q.x, 0.f) * g;
            float v1 = fmaxf(hacc[mi][ni][j * 4 + 1] + b1q.y, 0.f) * g;
            float v2 = fmaxf(hacc[mi][ni][j * 4 + 2] + b1q.z, 0.f) * g;
            float v3 = fmaxf(hacc[mi][ni][j * 4 + 3] + b1q.w, 0.f) * g;
            *reinterpret_cast<uint2*>(hdst + wbase + ni * (32 * ROWB) + mi * 64 + j * 16) =
                make_uint2(pk2bf(v0, v1), pk2bf(v2, v3));
          }
        }
      }
      BARRIER();  // hb[(e+1)&1] ready; hb[e&1] free for overwrite next segment
    }
  }

  // fold Sum_e gate[t][e] * b2[e][d] once
#pragma unroll
  for (int e = 0; e < NE; ++e) {
    float ge0 = g_lds[l31 * 9 + e];
    float ge1 = g_lds[(32 + l31) * 9 + e];
#pragma unroll
    for (int mi = 0; mi < 2; ++mi)
#pragma unroll
      for (int j = 0; j < 4; ++j) {
        float4 b2q = *reinterpret_cast<const float4*>(
            b2 + e * DM + w * 64 + mi * 32 + j * 8 + hi * 4);
        acc[mi][0][j * 4 + 0] += ge0 * b2q.x;
        acc[mi][0][j * 4 + 1] += ge0 * b2q.y;
        acc[mi][0][j * 4 + 2] += ge0 * b2q.z;
        acc[mi][0][j * 4 + 3] += ge0 * b2q.w;
        acc[mi][1][j * 4 + 0] += ge1 * b2q.x;
        acc[mi][1][j * 4 + 1] += ge1 * b2q.y;
        acc[mi][1][j * 4 + 2] += ge1 * b2q.z;
        acc[mi][1][j * 4 + 3] += ge1 * b2q.w;
      }
  }

  // write out: per (mi,ni,j) a float4 of consecutive d
#pragma unroll
  for (int ni = 0; ni < 2; ++ni) {
    int t = m0 + ni * 32 + l31;
#pragma unroll
    for (int mi = 0; mi < 2; ++mi)
#pragma unroll
      for (int j = 0; j < 4; ++j) {
        f32x4 v;
        v[0] = acc[mi][ni][j * 4 + 0];
        v[1] = acc[mi][ni][j * 4 + 1];
        v[2] = acc[mi][ni][j * 4 + 2];
        v[3] = acc[mi][ni][j * 4 + 3];
        *reinterpret_cast<f32x4*>(out + (size_t)t * DM + w * 64 + mi * 32 + j * 8 + hi * 4) = v;
      }
  }
#undef BARRIER
}

extern "C" void kernel_launch(void* const* d_in, const int* in_sizes, int n_in,
                              void* d_out, int out_size, void* d_ws, size_t ws_size,
                              hipStream_t stream) {
  const float* x  = (const float*)d_in[0];
  const float* W1 = (const float*)d_in[1];
  const float* b1 = (const float*)d_in[2];
  const float* W2 = (const float*)d_in[3];
  const float* b2 = (const float*)d_in[4];
  const float* Wg = (const float*)d_in[5];
  const float* bg = (const float*)d_in[6];
  float* out = (float*)d_out;

  float* gates = (float*)d_ws;                               // 512 KiB
  ushort* W1F = (ushort*)((char*)d_ws + 524288);             // 4 MiB
  ushort* W2F = (ushort*)((char*)d_ws + 4718592);            // 4 MiB
  ushort* XF  = (ushort*)((char*)d_ws + 8912896);            // 16 MiB

  hipFuncSetAttribute((const void*)moe_main_kernel,
                      hipFuncAttributeMaxDynamicSharedMemorySize, 151808);

  gates_kernel<<<T_TOK / 4, 256, 0, stream>>>(x, Wg, bg, gates);
  reorder_w_kernel<<<1024, 256, 0, stream>>>(W1, W1F);
  reorder_w_kernel<<<1024, 256, 0, stream>>>(W2, W2F);
  reorder_x_kernel<<<4096, 256, 0, stream>>>(x, XF);  // exactly 2^20 threads
  moe_main_kernel<<<T_TOK / BM, 512, 151808, stream>>>(XF, W1F, b1, W2F, b2, gates, out);
}

// Round 12
// 202.410 us; speedup vs baseline: 1.2350x; 1.2350x over previous
//
#include <hip/hip_runtime.h>

typedef __attribute__((ext_vector_type(8))) short short8;
typedef __attribute__((ext_vector_type(4))) float f32x4;
typedef __attribute__((ext_vector_type(16))) float f32x16;

#define T_TOK 16384
#define DM 512
#define NE 8
#define BM 32
#define ROWB 1040  // padded LDS row stride: 65*16B

__device__ __forceinline__ ushort f2bf(float v) {
  unsigned u = __float_as_uint(v);
  return (ushort)((u + 0x7FFFu + ((u >> 16) & 1u)) >> 16);
}

__device__ __forceinline__ unsigned pk2bf(float a, float b) {
  unsigned r;
  asm("v_cvt_pk_bf16_f32 %0, %1, %2" : "=v"(r) : "v"(a), "v"(b));
  return r;
}

#define MF(d, a, b) d = __builtin_amdgcn_mfma_f32_32x32x16_bf16(a, b, d, 0, 0, 0)

// ---------------- gating: logits + softmax, one wave per token ----------------
__global__ void gates_kernel(const float* __restrict__ x, const float* __restrict__ Wg,
                             const float* __restrict__ bg, float* __restrict__ gates) {
  int wid = (int)((blockIdx.x * blockDim.x + threadIdx.x) >> 6);
  int lane = threadIdx.x & 63;
  if (wid >= T_TOK) return;
  const float* xt = x + (size_t)wid * DM;
  float a[NE];
#pragma unroll
  for (int e = 0; e < NE; ++e) a[e] = 0.f;
  for (int d = lane; d < DM; d += 64) {
    float xv = xt[d];
    const float* wr = Wg + d * NE;
#pragma unroll
    for (int e = 0; e < NE; ++e) a[e] += xv * wr[e];
  }
#pragma unroll
  for (int e = 0; e < NE; ++e) {
#pragma unroll
    for (int off = 32; off > 0; off >>= 1) a[e] += __shfl_xor(a[e], off, 64);
  }
  float m = -1e30f;
#pragma unroll
  for (int e = 0; e < NE; ++e) { a[e] += bg[e]; m = fmaxf(m, a[e]); }
  float s = 0.f;
#pragma unroll
  for (int e = 0; e < NE; ++e) { a[e] = __expf(a[e] - m); s += a[e]; }
  float inv = 1.f / s;
  if (lane < NE) gates[(size_t)wid * NE + lane] = a[lane] * inv;
}

// -------- weight reorder: W[e][k][n] fp32 -> 32x32x16 A-fragment-major bf16 ----
// chunkid = (e*32 + kh)*16 + ft ; lane l holds
// W[e][kh*16 + (l>>5)*8 + j][ft*32 + (l&31)]  for j=0..7 (bf16).
__global__ void reorder_w_kernel(const float* __restrict__ W, ushort* __restrict__ WF) {
  int c = blockIdx.x * blockDim.x + threadIdx.x;  // 262144 threads
  int l = c & 63;
  int chunk = c >> 6;
  int ft = chunk & 15;
  int kh = (chunk >> 4) & 31;
  int e = chunk >> 9;
  int n = ft * 32 + (l & 31);
  int k0 = kh * 16 + (l >> 5) * 8;
  const float* src = W + ((size_t)e * DM + k0) * DM + n;
  short8 v;
#pragma unroll
  for (int j = 0; j < 8; ++j) v[j] = (short)f2bf(src[(size_t)j * DM]);
  *reinterpret_cast<short8*>(WF + (size_t)c * 8) = v;
}

// ---------------- fused MoE main kernel ----------------
// 512 blocks x 256 threads (4 waves, BM=32 tokens). Wave w owns cols
// [w*128, w*128+128). LDS 67.7KB -> 2 blocks/CU co-resident: each SIMD hosts
// one wave from each block with INDEPENDENT barriers -> one block's epilogue/
// barrier drain is covered by the other block's MFMAs.
// Half-kt pipeline: wbh[3][4] 2-ahead weight prefetch, abh[2] act dbuf.
__global__ __launch_bounds__(256, 2) void moe_main_kernel(
    const float* __restrict__ x, const ushort* __restrict__ W1F,
    const float* __restrict__ b1, const ushort* __restrict__ W2F,
    const float* __restrict__ b2, const float* __restrict__ gates,
    float* __restrict__ out) {
  extern __shared__ char smem[];
  char* x_lds = smem;                       // 32 * 1040 = 33280
  char* h_lds = smem + 33280;               // 33280
  float* g_lds = (float*)(smem + 66560);    // [32][9] f32 = 1152

  const int tid = threadIdx.x;
  const int lane = tid & 63;
  const int w = tid >> 6;        // wave 0..3
  const int hi = lane >> 5;
  const int l31 = lane & 31;
  const int m0 = blockIdx.x * BM;
  const int c0 = w * 128;        // this wave's output-col base

  const unsigned abase = (unsigned)l31 * ROWB + (unsigned)hi * 16;
  const unsigned wbase = (unsigned)l31 * ROWB + (unsigned)(c0 * 2 + hi * 8);

#define BARRIER()                                        \
  do {                                                   \
    asm volatile("s_waitcnt lgkmcnt(0)" ::: "memory");   \
    __builtin_amdgcn_s_barrier();                        \
  } while (0)

  {  // gates -> LDS (padded stride 9): 256 threads cover 32x8
    int t = tid >> 3, e = tid & 7;
    g_lds[t * 9 + e] = gates[(size_t)(m0 + t) * NE + e];
  }

  // stage x tile: fp32 -> bf16 via cvt_pk, padded rows (32 rows x 128 float4)
  for (int i = tid; i < BM * DM / 4; i += 256) {
    int t = i >> 7;
    int kd = (i & 127) * 4;
    float4 v = *reinterpret_cast<const float4*>(x + ((size_t)(m0 + t) << 9) + kd);
    *reinterpret_cast<uint2*>(x_lds + (unsigned)(t * ROWB + kd * 2)) =
        make_uint2(pk2bf(v.x, v.y), pk2bf(v.z, v.w));
  }
  BARRIER();

  const short8* wp1 = reinterpret_cast<const short8*>(W1F) + w * 4 * 64 + lane;
  const short8* wp2 = reinterpret_cast<const short8*>(W2F) + w * 4 * 64 + lane;

  f32x16 acc[4];
#pragma unroll
  for (int mi = 0; mi < 4; ++mi)
#pragma unroll
    for (int i = 0; i < 16; ++i) acc[mi][i] = 0.f;

  short8 wbh[3][4];  // weight frags, 2-ahead rotation
  short8 abh[2];     // act frag, 1-ahead dbuf

  // e=0 G1 prologue: hh0 -> wbh[2], hh1 -> wbh[0]; act hh0 -> abh[0]
#pragma unroll
  for (int mi = 0; mi < 4; ++mi) {
    wbh[2][mi] = wp1[mi * 64];
    wbh[0][mi] = wp1[1024 + mi * 64];
  }
  abh[0] = *reinterpret_cast<const short8*>(x_lds + abase);

  for (int e = 0; e < NE; ++e) {
    const short8* we1 = wp1 + (size_t)e * 32768;
    const short8* we2 = wp2 + (size_t)e * 32768;

    // ---------- GEMM1: h^T[f][t] = sum_k W1[k][f] * x[t][k] ----------
    f32x16 hacc[4];
#pragma unroll
    for (int mi = 0; mi < 4; ++mi)
#pragma unroll
      for (int i = 0; i < 16; ++i) hacc[mi][i] = 0.f;

#pragma unroll
    for (int hh = 0; hh < 32; ++hh) {
      if (hh < 30) {
#pragma unroll
        for (int mi = 0; mi < 4; ++mi)
          wbh[(hh + 1) % 3][mi] = we1[(hh + 2) * 1024 + mi * 64];
      }
      if (hh < 31)
        abh[(hh + 1) & 1] = *reinterpret_cast<const short8*>(x_lds + abase + (hh + 1) * 32);
      __builtin_amdgcn_s_setprio(1);
#pragma unroll
      for (int mi = 0; mi < 4; ++mi) MF(hacc[mi], wbh[(hh + 2) % 3][mi], abh[hh & 1]);
      __builtin_amdgcn_s_setprio(0);
    }

    // W2(e) prologue: hh0 -> wbh[1], hh1 -> wbh[2] (stay in flight across barrier)
#pragma unroll
    for (int mi = 0; mi < 4; ++mi) {
      wbh[1][mi] = we2[mi * 64];
      wbh[2][mi] = we2[1024 + mi * 64];
    }

    // epilogue: h[t][f] = relu(hacc + b1[f]) * g[t] -> h_lds
    {
      float g = g_lds[l31 * 9 + e];
#pragma unroll
      for (int mi = 0; mi < 4; ++mi) {
#pragma unroll
        for (int j = 0; j < 4; ++j) {
          float4 b1q = *reinterpret_cast<const float4*>(
              b1 + e * DM + c0 + mi * 32 + j * 8 + hi * 4);
          float v0 = fmaxf(hacc[mi][j * 4 + 0] + b1q.x, 0.f) * g;
          float v1 = fmaxf(hacc[mi][j * 4 + 1] + b1q.y, 0.f) * g;
          float v2 = fmaxf(hacc[mi][j * 4 + 2] + b1q.z, 0.f) * g;
          float v3 = fmaxf(hacc[mi][j * 4 + 3] + b1q.w, 0.f) * g;
          *reinterpret_cast<uint2*>(h_lds + wbase + mi * 64 + j * 16) =
              make_uint2(pk2bf(v0, v1), pk2bf(v2, v3));
        }
      }
    }
    BARRIER();  // h(e) visible

    // ---------- GEMM2: acc[d][t] += sum_f W2[f][d] * h[t][f] ----------
    abh[0] = *reinterpret_cast<const short8*>(h_lds + abase);
#pragma unroll
    for (int hh = 0; hh < 32; ++hh) {
      if (hh < 30) {
#pragma unroll
        for (int mi = 0; mi < 4; ++mi)
          wbh[hh % 3][mi] = we2[(hh + 2) * 1024 + mi * 64];
      }
      if (hh < 31)
        abh[(hh + 1) & 1] = *reinterpret_cast<const short8*>(h_lds + abase + (hh + 1) * 32);
      __builtin_amdgcn_s_setprio(1);
#pragma unroll
      for (int mi = 0; mi < 4; ++mi) MF(acc[mi], wbh[(hh + 1) % 3][mi], abh[hh & 1]);
      __builtin_amdgcn_s_setprio(0);
    }

    // next-expert G1 prologue (in flight across barrier)
    if (e < NE - 1) {
      const short8* wn1 = we1 + 32768;
#pragma unroll
      for (int mi = 0; mi < 4; ++mi) {
        wbh[2][mi] = wn1[mi * 64];
        wbh[0][mi] = wn1[1024 + mi * 64];
      }
      abh[0] = *reinterpret_cast<const short8*>(x_lds + abase);
    }
    BARRIER();  // all h(e) reads done; h buffer free for epi(e+1)
  }

  // fold Sum_e gate[t][e] * b2[e][d] once
#pragma unroll
  for (int e = 0; e < NE; ++e) {
    float ge = g_lds[l31 * 9 + e];
#pragma unroll
    for (int mi = 0; mi < 4; ++mi)
#pragma unroll
      for (int j = 0; j < 4; ++j) {
        float4 b2q = *reinterpret_cast<const float4*>(
            b2 + e * DM + c0 + mi * 32 + j * 8 + hi * 4);
        acc[mi][j * 4 + 0] += ge * b2q.x;
        acc[mi][j * 4 + 1] += ge * b2q.y;
        acc[mi][j * 4 + 2] += ge * b2q.z;
        acc[mi][j * 4 + 3] += ge * b2q.w;
      }
  }

  // write out: per (mi,j) a float4 of consecutive d for token m0+l31
  {
    float* orow = out + (size_t)(m0 + l31) * DM + c0 + hi * 4;
#pragma unroll
    for (int mi = 0; mi < 4; ++mi)
#pragma unroll
      for (int j = 0; j < 4; ++j) {
        f32x4 v;
        v[0] = acc[mi][j * 4 + 0];
        v[1] = acc[mi][j * 4 + 1];
        v[2] = acc[mi][j * 4 + 2];
        v[3] = acc[mi][j * 4 + 3];
        *reinterpret_cast<f32x4*>(orow + mi * 32 + j * 8) = v;
      }
  }
#undef BARRIER
}

extern "C" void kernel_launch(void* const* d_in, const int* in_sizes, int n_in,
                              void* d_out, int out_size, void* d_ws, size_t ws_size,
                              hipStream_t stream) {
  const float* x  = (const float*)d_in[0];
  const float* W1 = (const float*)d_in[1];
  const float* b1 = (const float*)d_in[2];
  const float* W2 = (const float*)d_in[3];
  const float* b2 = (const float*)d_in[4];
  const float* Wg = (const float*)d_in[5];
  const float* bg = (const float*)d_in[6];
  float* out = (float*)d_out;

  float* gates = (float*)d_ws;                              // 512 KiB
  ushort* W1F = (ushort*)((char*)d_ws + 524288);            // 4 MiB
  ushort* W2F = (ushort*)((char*)d_ws + 524288 + 4194304);  // 4 MiB

  hipFuncSetAttribute((const void*)moe_main_kernel,
                      hipFuncAttributeMaxDynamicSharedMemorySize, 67712);

  gates_kernel<<<T_TOK / 4, 256, 0, stream>>>(x, Wg, bg, gates);
  reorder_w_kernel<<<1024, 256, 0, stream>>>(W1, W1F);
  reorder_w_kernel<<<1024, 256, 0, stream>>>(W2, W2F);
  moe_main_kernel<<<T_TOK / BM, 256, 67712, stream>>>(x, W1F, b1, W2F, b2, gates, out);
}

// Round 13
// 155.365 us; speedup vs baseline: 1.6089x; 1.3028x over previous
//
#include <hip/hip_runtime.h>

typedef __attribute__((ext_vector_type(8))) short short8;
typedef __attribute__((ext_vector_type(4))) float f32x4;
typedef __attribute__((ext_vector_type(16))) float f32x16;

#define T_TOK 16384
#define DM 512
#define NE 8
#define BM 64
#define ROWB 1040  // padded LDS row stride: 65*16B -> bank-slot rotates by 1/row

__device__ __forceinline__ ushort f2bf(float v) {
  unsigned u = __float_as_uint(v);
  return (ushort)((u + 0x7FFFu + ((u >> 16) & 1u)) >> 16);
}

__device__ __forceinline__ unsigned pk2bf(float a, float b) {
  unsigned r;
  asm("v_cvt_pk_bf16_f32 %0, %1, %2" : "=v"(r) : "v"(a), "v"(b));
  return r;
}

#define MF(d, a, b) d = __builtin_amdgcn_mfma_f32_32x32x16_bf16(a, b, d, 0, 0, 0)

// -------- weight reorder (W1 and W2 in one launch) --------
// per matrix: chunkid = (e*32 + kh)*16 + ft ; lane l holds
// W[e][kh*16 + (l>>5)*8 + j][ft*32 + (l&31)]  for j=0..7 (bf16).
__global__ void reorder_w_kernel(const float* __restrict__ W1, const float* __restrict__ W2,
                                 ushort* __restrict__ W1F, ushort* __restrict__ W2F) {
  int c = blockIdx.x * blockDim.x + threadIdx.x;  // 524288 threads
  int which = c >> 18;
  c &= (1 << 18) - 1;
  const float* W = which ? W2 : W1;
  ushort* WF = which ? W2F : W1F;
  int l = c & 63;
  int chunk = c >> 6;
  int ft = chunk & 15;
  int kh = (chunk >> 4) & 31;
  int e = chunk >> 9;
  int n = ft * 32 + (l & 31);
  int k0 = kh * 16 + (l >> 5) * 8;
  const float* src = W + ((size_t)e * DM + k0) * DM + n;
  short8 v;
#pragma unroll
  for (int j = 0; j < 8; ++j) v[j] = (short)f2bf(src[(size_t)j * DM]);
  *reinterpret_cast<short8*>(WF + (size_t)c * 8) = v;
}

// ---------------- fused MoE main kernel (gates computed in-kernel) ----------------
// 256 blocks x 512 threads (8 waves). Wave w owns output cols [w*64, w*64+64).
// 32x32x16 MFMA, swapped operands: D[f][t] = mfma(A=W-frag, B=act-frag).
// Raw s_barrier + lgkmcnt-only drain; padded LDS rows (1040B).
__global__ __launch_bounds__(512, 2) void moe_main_kernel(
    const float* __restrict__ x, const ushort* __restrict__ W1F,
    const float* __restrict__ b1, const ushort* __restrict__ W2F,
    const float* __restrict__ b2, const float* __restrict__ Wg,
    const float* __restrict__ bg, float* __restrict__ out) {
  extern __shared__ char smem[];
  char* x_lds = smem;                        // 66560
  char* h_lds = smem + 66560;                // 66560
  float* g_lds = (float*)(smem + 133120);    // [64][9] f32 = 2304
  float* wg_lds = (float*)(smem + 135424);   // [512][8] f32 = 16384

  const int tid = threadIdx.x;
  const int lane = tid & 63;
  const int w = tid >> 6;        // wave 0..7
  const int hi = lane >> 5;      // k-half
  const int l31 = lane & 31;
  const int m0 = blockIdx.x * BM;

  const unsigned abase = (unsigned)l31 * ROWB + (unsigned)hi * 16;
  const unsigned wbase = (unsigned)l31 * ROWB + (unsigned)(w * 128 + hi * 8);

#define BARRIER()                                        \
  do {                                                   \
    asm volatile("s_waitcnt lgkmcnt(0)" ::: "memory");   \
    __builtin_amdgcn_s_barrier();                        \
  } while (0)

#define LDACT(lds, kt, ks, ni) \
  (*reinterpret_cast<const short8*>((lds) + abase + (ni) * (32 * ROWB) + ((kt) * 64 + (ks) * 32)))

  const float bgv = bg[tid & 7];  // issued early, used in gate compute

  {  // Wg -> LDS ([d][e] row-major copy, 1024 float4s)
    float4* dst = (float4*)wg_lds;
    const float4* src = (const float4*)Wg;
    dst[tid] = src[tid];
    dst[tid + 512] = src[tid + 512];
  }

  // stage x tile: fp32 -> bf16 via cvt_pk, padded rows
  for (int i = tid; i < BM * DM / 4; i += 512) {
    int t = i >> 7;
    int kd = (i & 127) * 4;
    float4 v = *reinterpret_cast<const float4*>(x + ((size_t)(m0 + t) << 9) + kd);
    *reinterpret_cast<uint2*>(x_lds + (unsigned)(t * ROWB + kd * 2)) =
        make_uint2(pk2bf(v.x, v.y), pk2bf(v.z, v.w));
  }
  BARRIER();

  const short8* wp1 = reinterpret_cast<const short8*>(W1F) + w * 128 + lane;
  const short8* wp2 = reinterpret_cast<const short8*>(W2F) + w * 128 + lane;

  f32x16 acc[2][2];
#pragma unroll
  for (int mi = 0; mi < 2; ++mi)
#pragma unroll
    for (int ni = 0; ni < 2; ++ni)
#pragma unroll
      for (int i = 0; i < 16; ++i) acc[mi][ni][i] = 0.f;

  short8 wb[3][4], ab[2][4];

  // e=0 GEMM1 prologue: kt0 -> wb[2], kt1 -> wb[0]; act kt0 -> ab[0]
  // (issued BEFORE gate compute so L2 latency hides under it)
#pragma unroll
  for (int ks = 0; ks < 2; ++ks)
#pragma unroll
    for (int mi = 0; mi < 2; ++mi) {
      wb[2][ks * 2 + mi] = wp1[ks * 1024 + mi * 64];
      wb[0][ks * 2 + mi] = wp1[2048 + ks * 1024 + mi * 64];
    }
#pragma unroll
  for (int ks = 0; ks < 2; ++ks)
#pragma unroll
    for (int ni = 0; ni < 2; ++ni) ab[0][ks * 2 + ni] = LDACT(x_lds, 0, ks, ni);

  {  // gates: thread (t = tid>>3, e = tid&7); logit = x[t]. Wg[:,e] + bg[e]
    int t = tid >> 3, e = tid & 7;
    const char* xrow = x_lds + (unsigned)(t * ROWB);
    float lg = 0.f;
    for (int d0 = 0; d0 < DM; d0 += 8) {
      short8 xv = *reinterpret_cast<const short8*>(xrow + d0 * 2);
#pragma unroll
      for (int j = 0; j < 8; ++j) {
        float xf = __uint_as_float(((unsigned)(ushort)xv[j]) << 16);
        lg += xf * wg_lds[(d0 + j) * 8 + e];
      }
    }
    lg += bgv;
    float m = lg;
    m = fmaxf(m, __shfl_xor(m, 1, 8));
    m = fmaxf(m, __shfl_xor(m, 2, 8));
    m = fmaxf(m, __shfl_xor(m, 4, 8));
    float ex = __expf(lg - m);
    float s = ex;
    s += __shfl_xor(s, 1, 8);
    s += __shfl_xor(s, 2, 8);
    s += __shfl_xor(s, 4, 8);
    g_lds[t * 9 + e] = ex / s;
  }
  BARRIER();  // g_lds ready (read first in epilogue of e=0)

  for (int e = 0; e < NE; ++e) {
    const short8* we1 = wp1 + (size_t)e * 32768;
    const short8* we2 = wp2 + (size_t)e * 32768;

    // ---------- GEMM1: h^T[f][t] = sum_k W1[k][f] * x[t][k] ----------
    f32x16 hacc[2][2];
#pragma unroll
    for (int mi = 0; mi < 2; ++mi)
#pragma unroll
      for (int ni = 0; ni < 2; ++ni)
#pragma unroll
        for (int i = 0; i < 16; ++i) hacc[mi][ni][i] = 0.f;

#pragma unroll
    for (int kt = 0; kt < 16; ++kt) {
      if (kt < 14) {
#pragma unroll
        for (int ks = 0; ks < 2; ++ks)
#pragma unroll
          for (int mi = 0; mi < 2; ++mi)
            wb[(kt + 1) % 3][ks * 2 + mi] = we1[(kt + 2) * 2048 + ks * 1024 + mi * 64];
      }
      if (kt < 15) {
#pragma unroll
        for (int ks = 0; ks < 2; ++ks)
#pragma unroll
          for (int ni = 0; ni < 2; ++ni)
            ab[(kt + 1) % 2][ks * 2 + ni] = LDACT(x_lds, kt + 1, ks, ni);
      }
      __builtin_amdgcn_s_setprio(1);
#pragma unroll
      for (int ks = 0; ks < 2; ++ks)
#pragma unroll
        for (int mi = 0; mi < 2; ++mi)
#pragma unroll
          for (int ni = 0; ni < 2; ++ni)
            MF(hacc[mi][ni], wb[(kt + 2) % 3][ks * 2 + mi], ab[kt % 2][ks * 2 + ni]);
      __builtin_amdgcn_s_setprio(0);
    }

    // GEMM2 weight prologue (stays in flight across barrier): kt0 -> wb[1], kt1 -> wb[2]
#pragma unroll
    for (int ks = 0; ks < 2; ++ks)
#pragma unroll
      for (int mi = 0; mi < 2; ++mi) {
        wb[1][ks * 2 + mi] = we2[ks * 1024 + mi * 64];
        wb[2][ks * 2 + mi] = we2[2048 + ks * 1024 + mi * 64];
      }

    // epilogue: h[t][f] = relu(hacc + b1[f]) * g[t] -> h_lds (cvt_pk + b64 writes)
#pragma unroll
    for (int ni = 0; ni < 2; ++ni) {
      int t = ni * 32 + l31;
      float g = g_lds[t * 9 + e];
#pragma unroll
      for (int mi = 0; mi < 2; ++mi) {
#pragma unroll
        for (int j = 0; j < 4; ++j) {
          float4 b1q = *reinterpret_cast<const float4*>(
              b1 + e * DM + w * 64 + mi * 32 + j * 8 + hi * 4);
          float v0 = fmaxf(hacc[mi][ni][j * 4 + 0] + b1q.x, 0.f) * g;
          float v1 = fmaxf(hacc[mi][ni][j * 4 + 1] + b1q.y, 0.f) * g;
          float v2 = fmaxf(hacc[mi][ni][j * 4 + 2] + b1q.z, 0.f) * g;
          float v3 = fmaxf(hacc[mi][ni][j * 4 + 3] + b1q.w, 0.f) * g;
          *reinterpret_cast<uint2*>(h_lds + wbase + ni * (32 * ROWB) + mi * 64 + j * 16) =
              make_uint2(pk2bf(v0, v1), pk2bf(v2, v3));
        }
      }
    }
    BARRIER();

    // ---------- GEMM2: acc[d][t] += sum_f W2[f][d] * h[t][f] ----------
#pragma unroll
    for (int ks = 0; ks < 2; ++ks)
#pragma unroll
      for (int ni = 0; ni < 2; ++ni) ab[0][ks * 2 + ni] = LDACT(h_lds, 0, ks, ni);

#pragma unroll
    for (int kt = 0; kt < 16; ++kt) {
      if (kt < 14) {
#pragma unroll
        for (int ks = 0; ks < 2; ++ks)
#pragma unroll
          for (int mi = 0; mi < 2; ++mi)
            wb[kt % 3][ks * 2 + mi] = we2[(kt + 2) * 2048 + ks * 1024 + mi * 64];
      }
      if (kt < 15) {
#pragma unroll
        for (int ks = 0; ks < 2; ++ks)
#pragma unroll
          for (int ni = 0; ni < 2; ++ni)
            ab[(kt + 1) % 2][ks * 2 + ni] = LDACT(h_lds, kt + 1, ks, ni);
      }
      __builtin_amdgcn_s_setprio(1);
#pragma unroll
      for (int ks = 0; ks < 2; ++ks)
#pragma unroll
        for (int mi = 0; mi < 2; ++mi)
#pragma unroll
          for (int ni = 0; ni < 2; ++ni)
            MF(acc[mi][ni], wb[(kt + 1) % 3][ks * 2 + mi], ab[kt % 2][ks * 2 + ni]);
      __builtin_amdgcn_s_setprio(0);
    }

    // next-expert GEMM1 prologue (stays in flight across barrier)
    if (e < NE - 1) {
      const short8* wn1 = we1 + 32768;
#pragma unroll
      for (int ks = 0; ks < 2; ++ks)
#pragma unroll
        for (int mi = 0; mi < 2; ++mi) {
          wb[2][ks * 2 + mi] = wn1[ks * 1024 + mi * 64];
          wb[0][ks * 2 + mi] = wn1[2048 + ks * 1024 + mi * 64];
        }
#pragma unroll
      for (int ks = 0; ks < 2; ++ks)
#pragma unroll
        for (int ni = 0; ni < 2; ++ni) ab[0][ks * 2 + ni] = LDACT(x_lds, 0, ks, ni);
    }
    BARRIER();
  }

  // fold Sum_e gate[t][e] * b2[e][d] ONCE (outside the barrier-locked loop)
#pragma unroll
  for (int e = 0; e < NE; ++e) {
    float ge0 = g_lds[l31 * 9 + e];
    float ge1 = g_lds[(32 + l31) * 9 + e];
#pragma unroll
    for (int mi = 0; mi < 2; ++mi)
#pragma unroll
      for (int j = 0; j < 4; ++j) {
        float4 b2q = *reinterpret_cast<const float4*>(
            b2 + e * DM + w * 64 + mi * 32 + j * 8 + hi * 4);
        acc[mi][0][j * 4 + 0] += ge0 * b2q.x;
        acc[mi][0][j * 4 + 1] += ge0 * b2q.y;
        acc[mi][0][j * 4 + 2] += ge0 * b2q.z;
        acc[mi][0][j * 4 + 3] += ge0 * b2q.w;
        acc[mi][1][j * 4 + 0] += ge1 * b2q.x;
        acc[mi][1][j * 4 + 1] += ge1 * b2q.y;
        acc[mi][1][j * 4 + 2] += ge1 * b2q.z;
        acc[mi][1][j * 4 + 3] += ge1 * b2q.w;
      }
  }

  // write out: per (mi,ni,j) a float4 of consecutive d
#pragma unroll
  for (int ni = 0; ni < 2; ++ni) {
    int t = m0 + ni * 32 + l31;
#pragma unroll
    for (int mi = 0; mi < 2; ++mi)
#pragma unroll
      for (int j = 0; j < 4; ++j) {
        f32x4 v;
        v[0] = acc[mi][ni][j * 4 + 0];
        v[1] = acc[mi][ni][j * 4 + 1];
        v[2] = acc[mi][ni][j * 4 + 2];
        v[3] = acc[mi][ni][j * 4 + 3];
        *reinterpret_cast<f32x4*>(out + (size_t)t * DM + w * 64 + mi * 32 + j * 8 + hi * 4) = v;
      }
  }
#undef LDACT
#undef BARRIER
}

extern "C" void kernel_launch(void* const* d_in, const int* in_sizes, int n_in,
                              void* d_out, int out_size, void* d_ws, size_t ws_size,
                              hipStream_t stream) {
  const float* x  = (const float*)d_in[0];
  const float* W1 = (const float*)d_in[1];
  const float* b1 = (const float*)d_in[2];
  const float* W2 = (const float*)d_in[3];
  const float* b2 = (const float*)d_in[4];
  const float* Wg = (const float*)d_in[5];
  const float* bg = (const float*)d_in[6];
  float* out = (float*)d_out;

  ushort* W1F = (ushort*)d_ws;                    // 4 MiB
  ushort* W2F = (ushort*)((char*)d_ws + 4194304); // 4 MiB

  hipFuncSetAttribute((const void*)moe_main_kernel,
                      hipFuncAttributeMaxDynamicSharedMemorySize, 151808);

  reorder_w_kernel<<<2048, 256, 0, stream>>>(W1, W2, W1F, W2F);
  moe_main_kernel<<<T_TOK / BM, 512, 151808, stream>>>(x, W1F, b1, W2F, b2, Wg, bg, out);
}

// Round 14
// 152.515 us; speedup vs baseline: 1.6390x; 1.0187x over previous
//
#include <hip/hip_runtime.h>

typedef __attribute__((ext_vector_type(8))) short short8;
typedef __attribute__((ext_vector_type(4))) float f32x4;
typedef __attribute__((ext_vector_type(16))) float f32x16;

#define T_TOK 16384
#define DM 512
#define NE 8
#define BM 64
#define ROWB 1040  // padded LDS row stride: 65*16B -> bank-slot rotates by 1/row

__device__ __forceinline__ ushort f2bf(float v) {
  unsigned u = __float_as_uint(v);
  return (ushort)((u + 0x7FFFu + ((u >> 16) & 1u)) >> 16);
}

__device__ __forceinline__ unsigned pk2bf(float a, float b) {
  unsigned r;
  asm("v_cvt_pk_bf16_f32 %0, %1, %2" : "=v"(r) : "v"(a), "v"(b));
  return r;
}

#define MF(d, a, b) d = __builtin_amdgcn_mfma_f32_32x32x16_bf16(a, b, d, 0, 0, 0)

// -------- weight reorder (W1, W2, and zero-padded Wg in one launch) --------
// W1/W2: chunkid = (e*32 + kh)*16 + ft ; lane l holds
//   W[e][kh*16 + (l>>5)*8 + j][ft*32 + (l&31)]  for j=0..7 (bf16).
// WgF (A-frag for gate MFMA): frag kt (0..31); lane l holds
//   Wg[kt*16 + (l>>5)*8 + j][l&31] for col<8 else 0.
__global__ void reorder_w_kernel(const float* __restrict__ W1, const float* __restrict__ W2,
                                 const float* __restrict__ Wg,
                                 ushort* __restrict__ W1F, ushort* __restrict__ W2F,
                                 ushort* __restrict__ WgF) {
  int c = blockIdx.x * blockDim.x + threadIdx.x;  // 526336 threads (2056 blocks)
  if (c < 524288) {
    int which = c >> 18;
    c &= (1 << 18) - 1;
    const float* W = which ? W2 : W1;
    ushort* WF = which ? W2F : W1F;
    int l = c & 63;
    int chunk = c >> 6;
    int ft = chunk & 15;
    int kh = (chunk >> 4) & 31;
    int e = chunk >> 9;
    int n = ft * 32 + (l & 31);
    int k0 = kh * 16 + (l >> 5) * 8;
    const float* src = W + ((size_t)e * DM + k0) * DM + n;
    short8 v;
#pragma unroll
    for (int j = 0; j < 8; ++j) v[j] = (short)f2bf(src[(size_t)j * DM]);
    *reinterpret_cast<short8*>(WF + (size_t)c * 8) = v;
  } else {
    int c2 = c - 524288;  // 0..2047
    int l = c2 & 63;
    int kt = c2 >> 6;     // 0..31
    int col = l & 31;
    int k0 = kt * 16 + (l >> 5) * 8;
    short8 v;
#pragma unroll
    for (int j = 0; j < 8; ++j)
      v[j] = (col < NE) ? (short)f2bf(Wg[(size_t)(k0 + j) * NE + col]) : (short)0;
    *reinterpret_cast<short8*>(WgF + (size_t)c2 * 8) = v;
  }
}

// ---------------- fused MoE main kernel (gates via wave-0 MFMA) ----------------
// 256 blocks x 512 threads (8 waves). Wave w owns output cols [w*64, w*64+64).
// 32x32x16 MFMA, swapped operands: D[f][t] = mfma(A=W-frag, B=act-frag).
// Raw s_barrier + lgkmcnt-only drain; padded LDS rows (1040B).
__global__ __launch_bounds__(512, 2) void moe_main_kernel(
    const float* __restrict__ x, const ushort* __restrict__ W1F,
    const float* __restrict__ b1, const ushort* __restrict__ W2F,
    const float* __restrict__ b2, const ushort* __restrict__ WgF,
    const float* __restrict__ bg, float* __restrict__ out) {
  extern __shared__ char smem[];
  char* x_lds = smem;                        // 66560
  char* h_lds = smem + 66560;                // 66560
  float* g_lds = (float*)(smem + 133120);    // [64][9] f32 = 2304
  float* b1_lds = (float*)(smem + 135424);   // [8][512] f32 = 16384

  const int tid = threadIdx.x;
  const int lane = tid & 63;
  const int w = tid >> 6;        // wave 0..7
  const int hi = lane >> 5;      // k-half
  const int l31 = lane & 31;
  const int m0 = blockIdx.x * BM;

  const unsigned abase = (unsigned)l31 * ROWB + (unsigned)hi * 16;
  const unsigned wbase = (unsigned)l31 * ROWB + (unsigned)(w * 128 + hi * 8);

#define BARRIER()                                        \
  do {                                                   \
    asm volatile("s_waitcnt lgkmcnt(0)" ::: "memory");   \
    __builtin_amdgcn_s_barrier();                        \
  } while (0)

#define LDACT(lds, kt, ks, ni) \
  (*reinterpret_cast<const short8*>((lds) + abase + (ni) * (32 * ROWB) + ((kt) * 64 + (ks) * 32)))

  {  // b1 -> LDS (4096 floats = 1024 float4)
    float4* dst = (float4*)b1_lds;
    const float4* src = (const float4*)b1;
    dst[tid] = src[tid];
    dst[tid + 512] = src[tid + 512];
  }

  // stage x tile: fp32 -> bf16 via cvt_pk, padded rows
  for (int i = tid; i < BM * DM / 4; i += 512) {
    int t = i >> 7;
    int kd = (i & 127) * 4;
    float4 v = *reinterpret_cast<const float4*>(x + ((size_t)(m0 + t) << 9) + kd);
    *reinterpret_cast<uint2*>(x_lds + (unsigned)(t * ROWB + kd * 2)) =
        make_uint2(pk2bf(v.x, v.y), pk2bf(v.z, v.w));
  }
  BARRIER();

  const short8* wp1 = reinterpret_cast<const short8*>(W1F) + w * 128 + lane;
  const short8* wp2 = reinterpret_cast<const short8*>(W2F) + w * 128 + lane;

  f32x16 acc[2][2];
#pragma unroll
  for (int mi = 0; mi < 2; ++mi)
#pragma unroll
    for (int ni = 0; ni < 2; ++ni)
#pragma unroll
      for (int i = 0; i < 16; ++i) acc[mi][ni][i] = 0.f;

  short8 wb[3][4], ab[2][4];

  // e=0 GEMM1 prologue: kt0 -> wb[2], kt1 -> wb[0]; act kt0 -> ab[0]
#pragma unroll
  for (int ks = 0; ks < 2; ++ks)
#pragma unroll
    for (int mi = 0; mi < 2; ++mi) {
      wb[2][ks * 2 + mi] = wp1[ks * 1024 + mi * 64];
      wb[0][ks * 2 + mi] = wp1[2048 + ks * 1024 + mi * 64];
    }
#pragma unroll
  for (int ks = 0; ks < 2; ++ks)
#pragma unroll
    for (int ni = 0; ni < 2; ++ni) ab[0][ks * 2 + ni] = LDACT(x_lds, 0, ks, ni);

  if (w == 0) {
    // gates on wave 0: D[e][t] = sum_k Wg[k][e] * x[t][k] via 64 MFMAs.
    // A = WgF frag (rows e, cols 8..31 zero), B = x frags (cols t).
    const short8* wgf = reinterpret_cast<const short8*>(WgF) + lane;
    f32x16 ga[2];
#pragma unroll
    for (int i = 0; i < 16; ++i) { ga[0][i] = 0.f; ga[1][i] = 0.f; }
    short8 wgb[2];
    wgb[0] = wgf[0];
#pragma unroll
    for (int s = 0; s < 32; ++s) {
      if (s < 31) wgb[(s + 1) & 1] = wgf[(s + 1) * 64];
      MF(ga[0], wgb[s & 1], LDACT(x_lds, s >> 1, s & 1, 0));
      MF(ga[1], wgb[s & 1], LDACT(x_lds, s >> 1, s & 1, 1));
    }
    // softmax over e for each token t = ni*32 + l31; lane holds e = r + 4*hi (r=0..3)
    float4 bgq = *reinterpret_cast<const float4*>(bg + hi * 4);
    float bgv[4] = {bgq.x, bgq.y, bgq.z, bgq.w};
#pragma unroll
    for (int ni = 0; ni < 2; ++ni) {
      float lg[4];
#pragma unroll
      for (int r = 0; r < 4; ++r) lg[r] = ga[ni][r] + bgv[r];
      float m = fmaxf(fmaxf(lg[0], lg[1]), fmaxf(lg[2], lg[3]));
      m = fmaxf(m, __shfl_xor(m, 32));
      float ex[4], s = 0.f;
#pragma unroll
      for (int r = 0; r < 4; ++r) { ex[r] = __expf(lg[r] - m); s += ex[r]; }
      s += __shfl_xor(s, 32);
      float inv = 1.f / s;
      int t = ni * 32 + l31;
#pragma unroll
      for (int r = 0; r < 4; ++r) g_lds[t * 9 + r + 4 * hi] = ex[r] * inv;
    }
  }
  BARRIER();  // g_lds ready

  for (int e = 0; e < NE; ++e) {
    const short8* we1 = wp1 + (size_t)e * 32768;
    const short8* we2 = wp2 + (size_t)e * 32768;

    // ---------- GEMM1: h^T[f][t] = sum_k W1[k][f] * x[t][k] ----------
    f32x16 hacc[2][2];
#pragma unroll
    for (int mi = 0; mi < 2; ++mi)
#pragma unroll
      for (int ni = 0; ni < 2; ++ni)
#pragma unroll
        for (int i = 0; i < 16; ++i) hacc[mi][ni][i] = 0.f;

#pragma unroll
    for (int kt = 0; kt < 16; ++kt) {
      if (kt < 14) {
#pragma unroll
        for (int ks = 0; ks < 2; ++ks)
#pragma unroll
          for (int mi = 0; mi < 2; ++mi)
            wb[(kt + 1) % 3][ks * 2 + mi] = we1[(kt + 2) * 2048 + ks * 1024 + mi * 64];
      }
      if (kt < 15) {
#pragma unroll
        for (int ks = 0; ks < 2; ++ks)
#pragma unroll
          for (int ni = 0; ni < 2; ++ni)
            ab[(kt + 1) % 2][ks * 2 + ni] = LDACT(x_lds, kt + 1, ks, ni);
      }
      __builtin_amdgcn_s_setprio(1);
#pragma unroll
      for (int ks = 0; ks < 2; ++ks)
#pragma unroll
        for (int mi = 0; mi < 2; ++mi)
#pragma unroll
          for (int ni = 0; ni < 2; ++ni)
            MF(hacc[mi][ni], wb[(kt + 2) % 3][ks * 2 + mi], ab[kt % 2][ks * 2 + ni]);
      __builtin_amdgcn_s_setprio(0);
    }

    // GEMM2 weight prologue (stays in flight across barrier): kt0 -> wb[1], kt1 -> wb[2]
#pragma unroll
    for (int ks = 0; ks < 2; ++ks)
#pragma unroll
      for (int mi = 0; mi < 2; ++mi) {
        wb[1][ks * 2 + mi] = we2[ks * 1024 + mi * 64];
        wb[2][ks * 2 + mi] = we2[2048 + ks * 1024 + mi * 64];
      }

    // epilogue: h[t][f] = relu(hacc + b1[f]) * g[t] -> h_lds (cvt_pk + b64 writes)
#pragma unroll
    for (int ni = 0; ni < 2; ++ni) {
      int t = ni * 32 + l31;
      float g = g_lds[t * 9 + e];
#pragma unroll
      for (int mi = 0; mi < 2; ++mi) {
#pragma unroll
        for (int j = 0; j < 4; ++j) {
          float4 b1q = *reinterpret_cast<const float4*>(
              b1_lds + e * DM + w * 64 + mi * 32 + j * 8 + hi * 4);
          float v0 = fmaxf(hacc[mi][ni][j * 4 + 0] + b1q.x, 0.f) * g;
          float v1 = fmaxf(hacc[mi][ni][j * 4 + 1] + b1q.y, 0.f) * g;
          float v2 = fmaxf(hacc[mi][ni][j * 4 + 2] + b1q.z, 0.f) * g;
          float v3 = fmaxf(hacc[mi][ni][j * 4 + 3] + b1q.w, 0.f) * g;
          *reinterpret_cast<uint2*>(h_lds + wbase + ni * (32 * ROWB) + mi * 64 + j * 16) =
              make_uint2(pk2bf(v0, v1), pk2bf(v2, v3));
        }
      }
    }
    BARRIER();

    // ---------- GEMM2: acc[d][t] += sum_f W2[f][d] * h[t][f] ----------
#pragma unroll
    for (int ks = 0; ks < 2; ++ks)
#pragma unroll
      for (int ni = 0; ni < 2; ++ni) ab[0][ks * 2 + ni] = LDACT(h_lds, 0, ks, ni);

#pragma unroll
    for (int kt = 0; kt < 16; ++kt) {
      if (kt < 14) {
#pragma unroll
        for (int ks = 0; ks < 2; ++ks)
#pragma unroll
          for (int mi = 0; mi < 2; ++mi)
            wb[kt % 3][ks * 2 + mi] = we2[(kt + 2) * 2048 + ks * 1024 + mi * 64];
      }
      if (kt < 15) {
#pragma unroll
        for (int ks = 0; ks < 2; ++ks)
#pragma unroll
          for (int ni = 0; ni < 2; ++ni)
            ab[(kt + 1) % 2][ks * 2 + ni] = LDACT(h_lds, kt + 1, ks, ni);
      }
      __builtin_amdgcn_s_setprio(1);
#pragma unroll
      for (int ks = 0; ks < 2; ++ks)
#pragma unroll
        for (int mi = 0; mi < 2; ++mi)
#pragma unroll
          for (int ni = 0; ni < 2; ++ni)
            MF(acc[mi][ni], wb[(kt + 1) % 3][ks * 2 + mi], ab[kt % 2][ks * 2 + ni]);
      __builtin_amdgcn_s_setprio(0);
    }

    // next-expert GEMM1 prologue (stays in flight across barrier)
    if (e < NE - 1) {
      const short8* wn1 = we1 + 32768;
#pragma unroll
      for (int ks = 0; ks < 2; ++ks)
#pragma unroll
        for (int mi = 0; mi < 2; ++mi) {
          wb[2][ks * 2 + mi] = wn1[ks * 1024 + mi * 64];
          wb[0][ks * 2 + mi] = wn1[2048 + ks * 1024 + mi * 64];
        }
#pragma unroll
      for (int ks = 0; ks < 2; ++ks)
#pragma unroll
        for (int ni = 0; ni < 2; ++ni) ab[0][ks * 2 + ni] = LDACT(x_lds, 0, ks, ni);
    }
    BARRIER();
  }

  // fold Sum_e gate[t][e] * b2[e][d] ONCE (outside the barrier-locked loop)
#pragma unroll
  for (int e = 0; e < NE; ++e) {
    float ge0 = g_lds[l31 * 9 + e];
    float ge1 = g_lds[(32 + l31) * 9 + e];
#pragma unroll
    for (int mi = 0; mi < 2; ++mi)
#pragma unroll
      for (int j = 0; j < 4; ++j) {
        float4 b2q = *reinterpret_cast<const float4*>(
            b2 + e * DM + w * 64 + mi * 32 + j * 8 + hi * 4);
        acc[mi][0][j * 4 + 0] += ge0 * b2q.x;
        acc[mi][0][j * 4 + 1] += ge0 * b2q.y;
        acc[mi][0][j * 4 + 2] += ge0 * b2q.z;
        acc[mi][0][j * 4 + 3] += ge0 * b2q.w;
        acc[mi][1][j * 4 + 0] += ge1 * b2q.x;
        acc[mi][1][j * 4 + 1] += ge1 * b2q.y;
        acc[mi][1][j * 4 + 2] += ge1 * b2q.z;
        acc[mi][1][j * 4 + 3] += ge1 * b2q.w;
      }
  }

  // write out: per (mi,ni,j) a float4 of consecutive d
#pragma unroll
  for (int ni = 0; ni < 2; ++ni) {
    int t = m0 + ni * 32 + l31;
#pragma unroll
    for (int mi = 0; mi < 2; ++mi)
#pragma unroll
      for (int j = 0; j < 4; ++j) {
        f32x4 v;
        v[0] = acc[mi][ni][j * 4 + 0];
        v[1] = acc[mi][ni][j * 4 + 1];
        v[2] = acc[mi][ni][j * 4 + 2];
        v[3] = acc[mi][ni][j * 4 + 3];
        *reinterpret_cast<f32x4*>(out + (size_t)t * DM + w * 64 + mi * 32 + j * 8 + hi * 4) = v;
      }
  }
#undef LDACT
#undef BARRIER
}

extern "C" void kernel_launch(void* const* d_in, const int* in_sizes, int n_in,
                              void* d_out, int out_size, void* d_ws, size_t ws_size,
                              hipStream_t stream) {
  const float* x  = (const float*)d_in[0];
  const float* W1 = (const float*)d_in[1];
  const float* b1 = (const float*)d_in[2];
  const float* W2 = (const float*)d_in[3];
  const float* b2 = (const float*)d_in[4];
  const float* Wg = (const float*)d_in[5];
  const float* bg = (const float*)d_in[6];
  float* out = (float*)d_out;

  ushort* W1F = (ushort*)d_ws;                     // 4 MiB
  ushort* W2F = (ushort*)((char*)d_ws + 4194304);  // 4 MiB
  ushort* WgF = (ushort*)((char*)d_ws + 8388608);  // 32 KiB

  hipFuncSetAttribute((const void*)moe_main_kernel,
                      hipFuncAttributeMaxDynamicSharedMemorySize, 151808);

  reorder_w_kernel<<<2056, 256, 0, stream>>>(W1, W2, Wg, W1F, W2F, WgF);
  moe_main_kernel<<<T_TOK / BM, 512, 151808, stream>>>(x, W1F, b1, W2F, b2, WgF, bg, out);
}